// Round 13
// baseline (202.357 us; speedup 1.0000x reference)
//
#include <hip/hip_runtime.h>
#include <hip/hip_bf16.h>

// ---- types ----
typedef __bf16 bf16_t;
typedef __bf16 bf16x2 __attribute__((ext_vector_type(2)));
typedef __bf16 bf16x4 __attribute__((ext_vector_type(4)));
typedef __bf16 bf16x8 __attribute__((ext_vector_type(8)));
typedef float  f32x4  __attribute__((ext_vector_type(4)));

#define D_MODEL 1024
#define HEADS   16
#define HD      64
#define BB      2
#define TT      2048
#define MROWS   (BB*TT)   // 4096

#define GLDS16(g, l) __builtin_amdgcn_global_load_lds( \
    (const __attribute__((address_space(1))) void*)(g), \
    (__attribute__((address_space(3))) void*)(l), 16, 0, 0)

static __device__ __forceinline__ int pack_bf16(float a, float b) {
    bf16x2 t; t[0] = (bf16_t)a; t[1] = (bf16_t)b;
    return __builtin_bit_cast(int, t);
}

// ---------------- fused fp32 -> bf16 convert ----------------
__global__ __launch_bounds__(256) void cvt_all_kernel(const float* __restrict__ x,
                                                      const float* __restrict__ wq,
                                                      const float* __restrict__ wk,
                                                      const float* __restrict__ wv,
                                                      const float* __restrict__ wo,
                                                      bf16_t* __restrict__ dst) {
    const int i = blockIdx.x * 256 + threadIdx.x;   // vec4 index, total 2097152
    const float* src;
    int s;
    if (i < 1048576) { src = x; s = i; }
    else {
        int j = i - 1048576;
        int w = j >> 18;          // 262144 vec4 per weight
        s = j & 262143;
        src = (w == 0) ? wq : (w == 1) ? wk : (w == 2) ? wv : wo;
    }
    float4 v = reinterpret_cast<const float4*>(src)[s];
    bf16x4 o;
    o[0] = (bf16_t)v.x; o[1] = (bf16_t)v.y; o[2] = (bf16_t)v.z; o[3] = (bf16_t)v.w;
    reinterpret_cast<bf16x4*>(dst)[i] = o;
}

// ---------------- bf16 GEMM: C[M,N] = A[M,K] * B[N,K]^T ----------------
// MODE 0: fused QKV scatter (N=3072) -> [B,H,T,D]; Q pre-scaled by 0.125*log2e.
// MODE 2: fp32 row-major [M,N] (final output)
template<int MODE, int BN>
__global__ __launch_bounds__(256) void gemm_bt(const bf16_t* __restrict__ A,
                                               const bf16_t* __restrict__ Bw,
                                               void* __restrict__ Cout,
                                               int M, int N, int K) {
    constexpr int NI = BN / 32;
    __shared__ __align__(16) bf16_t As[128*32];
    __shared__ __align__(16) bf16_t Bs[BN*32];
    const int tid   = threadIdx.x;
    const int lane  = tid & 63;
    const int wave  = tid >> 6;
    const int col16 = lane & 15;
    const int quad  = lane >> 4;
    const int wrow  = (wave & 1) * 64;
    const int wcol  = (wave >> 1) * (BN / 2);
    const int bm    = blockIdx.y * 128;
    const int bn    = blockIdx.x * BN;

    const int lr = tid >> 2;
    const int lc = (tid & 3) * 8;

    const bf16_t* agp = &A [(size_t)(bm + lr)*K + lc];
    const bf16_t* bgp = &Bw[(size_t)(bn + lr)*K + lc];
    const size_t half = (size_t)64 * K;
    bf16_t* as_lo = &As[wave*512];
    bf16_t* as_hi = &As[2048 + wave*512];
    bf16_t* bs_lo = &Bs[wave*512];
    bf16_t* bs_hi = &Bs[2048 + wave*512];

    f32x4 acc[4][NI];
#pragma unroll
    for (int i = 0; i < 4; i++)
#pragma unroll
        for (int j = 0; j < NI; j++) acc[i][j] = (f32x4){0.f, 0.f, 0.f, 0.f};

    for (int k0 = 0; k0 < K; k0 += 32) {
        GLDS16(agp + k0,        as_lo);
        GLDS16(agp + half + k0, as_hi);
        GLDS16(bgp + k0,        bs_lo);
        if (BN == 128) GLDS16(bgp + half + k0, bs_hi);
        __syncthreads();

        bf16x8 af[4], bfr[NI];
#pragma unroll
        for (int mi = 0; mi < 4; mi++)
            af[mi] = *reinterpret_cast<const bf16x8*>(&As[(wrow + mi*16 + col16)*32 + quad*8]);
#pragma unroll
        for (int ni = 0; ni < NI; ni++)
            bfr[ni] = *reinterpret_cast<const bf16x8*>(&Bs[(wcol + ni*16 + col16)*32 + quad*8]);
#pragma unroll
        for (int mi = 0; mi < 4; mi++)
#pragma unroll
            for (int ni = 0; ni < NI; ni++)
                acc[mi][ni] = __builtin_amdgcn_mfma_f32_16x16x32_bf16(af[mi], bfr[ni], acc[mi][ni], 0, 0, 0);
        __syncthreads();
    }

#pragma unroll
    for (int mi = 0; mi < 4; mi++) {
#pragma unroll
        for (int r = 0; r < 4; r++) {
            const int gm = bm + wrow + mi*16 + quad*4 + r;
            const int t  = gm & (TT - 1);
            const int b  = gm >> 11;
#pragma unroll
            for (int ni = 0; ni < NI; ni++) {
                const int gn = bn + wcol + ni*16 + col16;
                float v = acc[mi][ni][r];
                if (MODE == 2) {
                    reinterpret_cast<float*>(Cout)[(size_t)gm * N + gn] = v;
                } else {
                    const int which = gn >> 10;       // 0=Q 1=K 2=V
                    if (which == 0) v *= 0.18033688f; // 0.125 * log2(e), fp32 pre-rounding
                    const int n = gn & 1023;
                    const int h = n >> 6, d = n & 63;
                    const size_t off = (size_t)(which == 2 ? 3 : which) * MROWS * D_MODEL;
                    bf16_t* base = reinterpret_cast<bf16_t*>(Cout) + off;
                    base[(((size_t)(b*HEADS + h))*TT + t)*HD + d] = (bf16_t)v;
                }
            }
        }
    }
}

// ---------------- V transpose: [B,H,T,D] -> [B,H,D,T] ----------------
__global__ __launch_bounds__(256) void transpose_v(const bf16_t* __restrict__ V,
                                                   bf16_t* __restrict__ Vt) {
    __shared__ bf16_t tile[64][72];
    const int tid = threadIdx.x;
    const int bh = blockIdx.y;
    const int t0 = blockIdx.x * 64;
    const bf16_t* src = V + ((size_t)bh * TT + t0) * HD;
#pragma unroll
    for (int i = 0; i < 2; i++) {
        const int r = i*32 + (tid >> 3), c = (tid & 7) * 8;
        *reinterpret_cast<bf16x8*>(&tile[r][c]) =
            *reinterpret_cast<const bf16x8*>(&src[(size_t)r * HD + c]);
    }
    __syncthreads();
    bf16_t* dst = Vt + (size_t)bh * HD * TT + t0;
#pragma unroll
    for (int i = 0; i < 2; i++) {
        const int d = i*32 + (tid >> 3), tc = (tid & 7) * 8;
        bf16x8 o;
#pragma unroll
        for (int j = 0; j < 8; j++) o[j] = tile[tc + j][d];
        *reinterpret_cast<bf16x8*>(&dst[(size_t)d * TT + tc]) = o;
    }
}

// ---------------- flash attention, LENGTH-EQUALIZED split ----------------
// R11 inner loop (measured best). Every qt>=16 block splits into two halves
// over keys ([0,m) and [m,qt+1), m=ceil((qt+1)/2)) so ALL 1536 blocks run
// <=16 tiles: R11's occupancy decayed to ~2 waves/SIMD as short partners
// drained, leaving the 32-tile anchor at ~3900 cyc/tile — equal lengths keep
// ~5 blocks/CU resident for the whole makespan. Split halves write
// UNNORMALIZED bf16 O-partials + fp32 l-partials to disjoint buffers (plain
// coalesced stores, NO atomics — R7 showed atomics write through to HBM);
// combine_kernel merges. No-max softmax partials are additive.
// R12 BUG FIX: partial-buffer q-index must be wave*16+col16 (wave offset was
// dropped -> 3/4 of Opart never written -> poison read).
// Grid map (stride-256 cyclic CU assignment, bh = bx&31 shared per CU):
//   bx<1024: split. p=bx>>5, half=p&1, pp=p>>1; qt = pp<8 ? 31-pp : 8+pp.
//   bx>=1024: direct. p=(bx-1024)>>5; qt = p<8 ? 15-p : p-8.
__global__ __launch_bounds__(256, 5) void attn_kernel(const bf16_t* __restrict__ Q,
                                                      const bf16_t* __restrict__ Kk,
                                                      const bf16_t* __restrict__ Vt,
                                                      bf16_t* __restrict__ O,
                                                      bf16_t* __restrict__ Opart,
                                                      float* __restrict__ Lpart) {
    __shared__ __align__(16) bf16_t Ks[2][64*64];   // [key][d-chunks], XOR-swizzled
    __shared__ __align__(16) bf16_t Vs[2][64*64];   // [d][key-chunks], XOR-swizzled

    const int tid   = threadIdx.x;
    const int lane  = tid & 63;
    const int wave  = tid >> 6;
    const int col16 = lane & 15;
    const int quad  = lane >> 4;

    const int bx = blockIdx.x;
    int bh, qt, kbeg, kend, half_ = 0, pairId = 0;
    bool split;
    if (bx < 1024) {
        split = true;
        bh = bx & 31;
        const int p  = bx >> 5;
        half_ = p & 1;
        const int pp = p >> 1;
        qt = (pp < 8) ? (31 - pp) : (8 + pp);   // 16..31
        const int m = (qt + 2) >> 1;            // ceil((qt+1)/2)
        kbeg = half_ ? m : 0;
        kend = half_ ? (qt + 1) : m;
        pairId = (qt - 16) * 32 + bh;
    } else {
        split = false;
        const int j = bx - 1024;
        bh = j & 31;
        const int p = j >> 5;                    // 0..15
        qt = (p < 8) ? (15 - p) : (p - 8);
        kbeg = 0; kend = qt + 1;
    }
    const int qb    = qt * 64;
    const int qbase = qb + wave * 16;

    const bf16_t* Qb = Q  + (size_t)bh * TT * HD;
    const bf16_t* Kb = Kk + (size_t)bh * TT * HD;
    const bf16_t* Vb = Vt + (size_t)bh * HD * TT;

    // Q fragments (B-operand layout B[k=d][n=q])
    bf16x8 qf0 = *reinterpret_cast<const bf16x8*>(&Qb[(size_t)(qbase + col16)*HD + quad*8]);
    bf16x8 qf1 = *reinterpret_cast<const bf16x8*>(&Qb[(size_t)(qbase + col16)*HD + 32 + quad*8]);

    // staging geometry: each shot = 256 threads x 16B = 4KB = 32 rows x 64 cols.
    const int srow = (tid >> 3) & 31;
    const int sg   = ((lane & 7) ^ (srow & 7)) * 8;

    auto stage = [&](int kt, int buf) {
        const int s0 = kt * 64;
        GLDS16(&Kb[(size_t)(s0 + srow)*HD + sg],        &Ks[buf][wave*512]);
        GLDS16(&Kb[(size_t)(s0 + srow + 32)*HD + sg],   &Ks[buf][2048 + wave*512]);
        GLDS16(&Vb[(size_t)srow*TT + s0 + sg],          &Vs[buf][wave*512]);
        GLDS16(&Vb[(size_t)(srow + 32)*TT + s0 + sg],   &Vs[buf][2048 + wave*512]);
    };

    f32x4 acc[4];    // out^T: acc[c][r] = O^T[d = c*16+quad*4+r][q = col16]
#pragma unroll
    for (int i = 0; i < 4; i++) acc[i] = (f32x4){0.f,0.f,0.f,0.f};
    float lsum = 0.f;

    const int x7 = col16 & 7;
    const int a1 = ((quad & 1) * 32 + col16) * 4;
    const int a2 = a1 + 64;
    const bool hi = quad >= 2;

    stage(kbeg, 0);
    __syncthreads();

    for (int kt = kbeg; kt < kend; kt++) {
        const int buf = (kt - kbeg) & 1;
        if (kt + 1 < kend) stage(kt + 1, buf ^ 1);
        const int s0 = kt * 64;
        const bool diag = (kt == qt);

        // ---- S^T = K Q^T, softmax (scale pre-baked into Q), pack P^T ----
        int pk[4][2];
#pragma unroll
        for (int c = 0; c < 4; c++) {
            bf16x8 k0 = *reinterpret_cast<const bf16x8*>(
                &Ks[buf][(c*16 + col16)*64 + ((0*4 + quad) ^ x7)*8]);
            bf16x8 k1 = *reinterpret_cast<const bf16x8*>(
                &Ks[buf][(c*16 + col16)*64 + ((1*4 + quad) ^ x7)*8]);
            f32x4 sv = __builtin_amdgcn_mfma_f32_16x16x32_bf16(k0, qf0, (f32x4){0.f,0.f,0.f,0.f}, 0, 0, 0);
            sv       = __builtin_amdgcn_mfma_f32_16x16x32_bf16(k1, qf1, sv, 0, 0, 0);

            float pr[4];
#pragma unroll
            for (int r = 0; r < 4; r++) pr[r] = exp2f(sv[r]);
            if (diag) {
#pragma unroll
                for (int r = 0; r < 4; r++)
                    if (s0 + c*16 + quad*4 + r > qbase + col16) pr[r] = 0.f;
            }
            lsum += (pr[0] + pr[1]) + (pr[2] + pr[3]);
            pk[c][0] = pack_bf16(pr[0], pr[1]);
            pk[c][1] = pack_bf16(pr[2], pr[3]);
        }

        // ---- PV: out^T += V^T P^T over 2 key-chunks of 32 ----
#pragma unroll
        for (int kc = 0; kc < 2; kc++) {
            int b0l = __builtin_amdgcn_ds_bpermute(a1, pk[2*kc][0]);
            int b0h = __builtin_amdgcn_ds_bpermute(a1, pk[2*kc+1][0]);
            int b1l = __builtin_amdgcn_ds_bpermute(a1, pk[2*kc][1]);
            int b1h = __builtin_amdgcn_ds_bpermute(a1, pk[2*kc+1][1]);
            int b2l = __builtin_amdgcn_ds_bpermute(a2, pk[2*kc][0]);
            int b2h = __builtin_amdgcn_ds_bpermute(a2, pk[2*kc+1][0]);
            int b3l = __builtin_amdgcn_ds_bpermute(a2, pk[2*kc][1]);
            int b3h = __builtin_amdgcn_ds_bpermute(a2, pk[2*kc+1][1]);
            int4 bi = { hi ? b0h : b0l, hi ? b1h : b1l, hi ? b2h : b2l, hi ? b3h : b3l };
            bf16x8 pf = __builtin_bit_cast(bf16x8, bi);
#pragma unroll
            for (int c = 0; c < 4; c++) {
                bf16x8 vf = *reinterpret_cast<const bf16x8*>(
                    &Vs[buf][(c*16 + col16)*64 + ((kc*4 + quad) ^ x7)*8]);
                acc[c] = __builtin_amdgcn_mfma_f32_16x16x32_bf16(vf, pf, acc[c], 0, 0, 0);
            }
        }
        __syncthreads();
    }

    // softmax denom partial across quads (same query col16)
    float l = lsum;
    l += __shfl_xor(l, 16);
    l += __shfl_xor(l, 32);

    if (split) {
        // unnormalized bf16 O-partial + fp32 l-partial, disjoint coalesced stores
        const int qloc = wave*16 + col16;            // R12 fix: include wave offset
        if (quad == 0) Lpart[(pairId*2 + half_)*64 + qloc] = l;
        bf16_t* Pb = &Opart[(((size_t)(pairId*2 + half_))*64 + qloc)*64 + quad*4];
#pragma unroll
        for (int c = 0; c < 4; c++) {
            bf16x4 o4;
#pragma unroll
            for (int r = 0; r < 4; r++) o4[r] = (bf16_t)acc[c][r];
            *reinterpret_cast<bf16x4*>(&Pb[c*16]) = o4;
        }
    } else {
        const float inv = 1.0f / l;
        const int b_ = bh >> 4, h = bh & 15;
        const int t = qbase + col16;
        bf16_t* Ob = &O[(((size_t)(b_*TT + t))*HEADS + h)*HD + quad*4];
#pragma unroll
        for (int c = 0; c < 4; c++) {
            bf16x4 o4;
#pragma unroll
            for (int r = 0; r < 4; r++) o4[r] = (bf16_t)(acc[c][r] * inv);
            *reinterpret_cast<bf16x4*>(&Ob[c*16]) = o4;
        }
    }
}

// ---------------- combine: merge split halves, normalize -> O ----------------
__global__ __launch_bounds__(256) void combine_kernel(const bf16_t* __restrict__ Opart,
                                                      const float* __restrict__ Lpart,
                                                      bf16_t* __restrict__ O) {
    const int idx = blockIdx.x * 256 + threadIdx.x;   // 0..262143
    const int d8 = (idx & 7) * 8;
    const int q  = (idx >> 3) & 63;
    const int pr = idx >> 9;                           // 0..511
    const int qt = 16 + (pr >> 5);
    const int bh = pr & 31;
    const float la = Lpart[(pr*2    )*64 + q];
    const float lb = Lpart[(pr*2 + 1)*64 + q];
    const float inv = 1.0f / (la + lb);
    bf16x8 a = *reinterpret_cast<const bf16x8*>(&Opart[(((size_t)(pr*2    ))*64 + q)*64 + d8]);
    bf16x8 b = *reinterpret_cast<const bf16x8*>(&Opart[(((size_t)(pr*2 + 1))*64 + q)*64 + d8]);
    bf16x8 o;
#pragma unroll
    for (int i = 0; i < 8; i++) o[i] = (bf16_t)(((float)a[i] + (float)b[i]) * inv);
    const int b_ = bh >> 4, h = bh & 15;
    const int t = qt*64 + q;
    *reinterpret_cast<bf16x8*>(&O[(((size_t)(b_*TT + t))*HEADS + h)*HD + d8]) = o;
}

// ---------------- launch ----------------
extern "C" void kernel_launch(void* const* d_in, const int* in_sizes, int n_in,
                              void* d_out, int out_size, void* d_ws, size_t ws_size,
                              hipStream_t stream) {
    const float* x  = (const float*)d_in[0];
    const float* Wq = (const float*)d_in[1];
    const float* Wk = (const float*)d_in[2];
    const float* Wv = (const float*)d_in[3];
    const float* Wo = (const float*)d_in[4];
    float* out = (float*)d_out;

    // workspace layout (bf16 elements), contiguous, 48 MB total.
    // Xb/Wqb (14 MB) are dead after the QKV GEMM; attn reuses them:
    //   Opart = 512 pairs x 2 halves x 64q x 64d bf16 = 8 MB   (over Xb)
    //   Lpart = 512 x 2 x 64 fp32 = 256 KB                      (over Wqb start)
    bf16_t* Xb  = (bf16_t*)d_ws;                       // 4M
    bf16_t* Wqb = Xb  + (size_t)MROWS * D_MODEL;       // 3M (Wq|Wk|Wv)
    bf16_t* Wob = Wqb + (size_t)3 * D_MODEL * D_MODEL; // 1M
    bf16_t* Qw  = Wob + (size_t)D_MODEL * D_MODEL;     // 4M  [B,H,T,D], pre-scaled
    bf16_t* Kw  = Qw  + (size_t)MROWS * D_MODEL;       // 4M  [B,H,T,D]
    bf16_t* Vt  = Kw  + (size_t)MROWS * D_MODEL;       // 4M  [B,H,D,T]
    bf16_t* Ow  = Vt  + (size_t)MROWS * D_MODEL;       // 4M  V-raw, then attn out [B,T,H,D]
    bf16_t* Opart = (bf16_t*)d_ws;
    float*  Lpart = (float*)((char*)d_ws + (size_t)8*1024*1024);

    // 1) convert all inputs to bf16
    cvt_all_kernel<<<(MROWS*D_MODEL + 4*D_MODEL*D_MODEL) / 4 / 256, 256, 0, stream>>>(
        x, Wq, Wk, Wv, Wo, Xb);

    // 2) fused QKV projection (V-raw lands in the Ow slot, coalesced)
    dim3 gqkv(3 * D_MODEL / 128, MROWS / 128);
    gemm_bt<0,128><<<gqkv, 256, 0, stream>>>(Xb, Wqb, Qw, MROWS, 3 * D_MODEL, D_MODEL);

    // 3) V transpose -> [B,H,D,T]
    dim3 gt(TT / 64, BB * HEADS);
    transpose_v<<<gt, 256, 0, stream>>>(Ow, Vt);

    // 4) flash attention, length-equalized split (1536 blocks)
    attn_kernel<<<dim3(1536), 256, 0, stream>>>(Qw, Kw, Vt, Ow, Opart, Lpart);

    // 5) combine split halves for t in [1024,2048)
    combine_kernel<<<dim3(1024), 256, 0, stream>>>(Opart, Lpart, Ow);

    // 6) output projection -> fp32 d_out (64-col tiles: 512 blocks = 2/CU)
    dim3 go(D_MODEL / 64, MROWS / 128);
    gemm_bt<2,64><<<go, 256, 0, stream>>>(Ow, Wob, out, MROWS, D_MODEL, D_MODEL);
}

// Round 14
// 191.703 us; speedup vs baseline: 1.0556x; 1.0556x over previous
//
#include <hip/hip_runtime.h>
#include <hip/hip_bf16.h>

// ---- types ----
typedef __bf16 bf16_t;
typedef __bf16 bf16x2 __attribute__((ext_vector_type(2)));
typedef __bf16 bf16x4 __attribute__((ext_vector_type(4)));
typedef __bf16 bf16x8 __attribute__((ext_vector_type(8)));
typedef float  f32x4  __attribute__((ext_vector_type(4)));

#define D_MODEL 1024
#define HEADS   16
#define HD      64
#define BB      2
#define TT      2048
#define MROWS   (BB*TT)   // 4096

#define GLDS16(g, l) __builtin_amdgcn_global_load_lds( \
    (const __attribute__((address_space(1))) void*)(g), \
    (__attribute__((address_space(3))) void*)(l), 16, 0, 0)

static __device__ __forceinline__ int pack_bf16(float a, float b) {
    bf16x2 t; t[0] = (bf16_t)a; t[1] = (bf16_t)b;
    return __builtin_bit_cast(int, t);
}

// ---------------- fused fp32 -> bf16 convert ----------------
__global__ __launch_bounds__(256) void cvt_all_kernel(const float* __restrict__ x,
                                                      const float* __restrict__ wq,
                                                      const float* __restrict__ wk,
                                                      const float* __restrict__ wv,
                                                      const float* __restrict__ wo,
                                                      bf16_t* __restrict__ dst) {
    const int i = blockIdx.x * 256 + threadIdx.x;   // vec4 index, total 2097152
    const float* src;
    int s;
    if (i < 1048576) { src = x; s = i; }
    else {
        int j = i - 1048576;
        int w = j >> 18;          // 262144 vec4 per weight
        s = j & 262143;
        src = (w == 0) ? wq : (w == 1) ? wk : (w == 2) ? wv : wo;
    }
    float4 v = reinterpret_cast<const float4*>(src)[s];
    bf16x4 o;
    o[0] = (bf16_t)v.x; o[1] = (bf16_t)v.y; o[2] = (bf16_t)v.z; o[3] = (bf16_t)v.w;
    reinterpret_cast<bf16x4*>(dst)[i] = o;
}

// ---------------- bf16 GEMM: C[M,N] = A[M,K] * B[N,K]^T ----------------
// MODE 0: fused QKV scatter (N=3072). Q (cols 0-1023) -> [B,H,T,D] pre-scaled
//         by 0.125*log2e; K (1024-2047) -> [B,H,T,D]; V (2048-3071) -> written
//         DIRECTLY TRANSPOSED to [B,H,D,T] via packed bf16x4 stores (the C/D
//         layout's row=quad*4+r gives 4 consecutive t per thread) — this
//         removes the separate transpose kernel entirely.
// MODE 2: fp32 row-major [M,N] (final output)
template<int MODE, int BN>
__global__ __launch_bounds__(256) void gemm_bt(const bf16_t* __restrict__ A,
                                               const bf16_t* __restrict__ Bw,
                                               void* __restrict__ Cout,
                                               int M, int N, int K) {
    constexpr int NI = BN / 32;
    __shared__ __align__(16) bf16_t As[128*32];
    __shared__ __align__(16) bf16_t Bs[BN*32];
    const int tid   = threadIdx.x;
    const int lane  = tid & 63;
    const int wave  = tid >> 6;
    const int col16 = lane & 15;
    const int quad  = lane >> 4;
    const int wrow  = (wave & 1) * 64;
    const int wcol  = (wave >> 1) * (BN / 2);
    const int bm    = blockIdx.y * 128;
    const int bn    = blockIdx.x * BN;

    const int lr = tid >> 2;
    const int lc = (tid & 3) * 8;

    const bf16_t* agp = &A [(size_t)(bm + lr)*K + lc];
    const bf16_t* bgp = &Bw[(size_t)(bn + lr)*K + lc];
    const size_t half = (size_t)64 * K;
    bf16_t* as_lo = &As[wave*512];
    bf16_t* as_hi = &As[2048 + wave*512];
    bf16_t* bs_lo = &Bs[wave*512];
    bf16_t* bs_hi = &Bs[2048 + wave*512];

    f32x4 acc[4][NI];
#pragma unroll
    for (int i = 0; i < 4; i++)
#pragma unroll
        for (int j = 0; j < NI; j++) acc[i][j] = (f32x4){0.f, 0.f, 0.f, 0.f};

    for (int k0 = 0; k0 < K; k0 += 32) {
        GLDS16(agp + k0,        as_lo);
        GLDS16(agp + half + k0, as_hi);
        GLDS16(bgp + k0,        bs_lo);
        if (BN == 128) GLDS16(bgp + half + k0, bs_hi);
        __syncthreads();

        bf16x8 af[4], bfr[NI];
#pragma unroll
        for (int mi = 0; mi < 4; mi++)
            af[mi] = *reinterpret_cast<const bf16x8*>(&As[(wrow + mi*16 + col16)*32 + quad*8]);
#pragma unroll
        for (int ni = 0; ni < NI; ni++)
            bfr[ni] = *reinterpret_cast<const bf16x8*>(&Bs[(wcol + ni*16 + col16)*32 + quad*8]);
#pragma unroll
        for (int mi = 0; mi < 4; mi++)
#pragma unroll
            for (int ni = 0; ni < NI; ni++)
                acc[mi][ni] = __builtin_amdgcn_mfma_f32_16x16x32_bf16(af[mi], bfr[ni], acc[mi][ni], 0, 0, 0);
        __syncthreads();
    }

    // epilogue: C/D layout col=lane&15, row=quad*4+reg
#pragma unroll
    for (int mi = 0; mi < 4; mi++) {
        const int gm0 = bm + wrow + mi*16 + quad*4;   // 4-aligned: t0..t0+3 same b
        const int t0  = gm0 & (TT - 1);
        const int b   = gm0 >> 11;                    // TT = 2048
#pragma unroll
        for (int ni = 0; ni < NI; ni++) {
            const int gn = bn + wcol + ni*16 + col16;
            if (MODE == 2) {
#pragma unroll
                for (int r = 0; r < 4; r++)
                    reinterpret_cast<float*>(Cout)[(size_t)(gm0 + r) * N + gn] = acc[mi][ni][r];
            } else {
                const int which = gn >> 10;       // 0=Q 1=K 2=V
                const int n = gn & 1023;
                const int h = n >> 6, d = n & 63;
                bf16_t* base = reinterpret_cast<bf16_t*>(Cout) + (size_t)which * MROWS * D_MODEL;
                if (which == 2) {
                    // V: direct transposed write, 4 consecutive t packed (8B)
                    bf16x4 v4;
#pragma unroll
                    for (int r = 0; r < 4; r++) v4[r] = (bf16_t)acc[mi][ni][r];
                    *reinterpret_cast<bf16x4*>(
                        &base[((size_t)(b*HEADS + h)*HD + d)*TT + t0]) = v4;
                } else {
                    const float sc = (which == 0) ? 0.18033688f : 1.0f;  // 0.125*log2(e)
#pragma unroll
                    for (int r = 0; r < 4; r++)
                        base[(((size_t)(b*HEADS + h))*TT + t0 + r)*HD + d] =
                            (bf16_t)(acc[mi][ni][r] * sc);
                }
            }
        }
    }
}

// ---------------- flash attention: 4 waves/block, 64 q-rows, 64-key tiles ----
// R11 configuration (measured best: 52.9 us). S^T = K·Q^T; P^T feeds the PV
// MFMA via in-wave ds_bpermute. Q pre-scaled by 0.125*log2e; no-max softmax.
// Q,K: [B,H,T,D] bf16.  Vt: [B,H,D,T].  O: [B,T,H,D].
// Grid packing: blocks {s, s+256, s+512, s+768} share a CU (stride-256 cyclic
// dispatch) and share bh = s&31 (L2 locality -> FETCH 12 MB). Balanced map:
// anchor 24+j with partners {7-j, 8+j, 23-j} -> 66 tiles on every CU.
__global__ __launch_bounds__(256, 5) void attn_kernel(const bf16_t* __restrict__ Q,
                                                      const bf16_t* __restrict__ Kk,
                                                      const bf16_t* __restrict__ Vt,
                                                      bf16_t* __restrict__ O) {
    __shared__ __align__(16) bf16_t Ks[2][64*64];   // [key][d-chunks], XOR-swizzled
    __shared__ __align__(16) bf16_t Vs[2][64*64];   // [d][key-chunks], XOR-swizzled

    const int tid   = threadIdx.x;
    const int lane  = tid & 63;
    const int wave  = tid >> 6;
    const int col16 = lane & 15;
    const int quad  = lane >> 4;

    const int bx = blockIdx.x;
    const int r_ = bx >> 8, s_ = bx & 255;
    const int bh = s_ & 31;
    const int j_ = s_ >> 5;
    int qt;
    if (r_ == 0)      qt = 24 + j_;   // anchors, dispatched first
    else if (r_ == 1) qt = 7 - j_;
    else if (r_ == 2) qt = 8 + j_;
    else              qt = 23 - j_;
    const int qb    = qt * 64;
    const int qbase = qb + wave * 16;
    const int nkt   = qt + 1;

    const bf16_t* Qb = Q  + (size_t)bh * TT * HD;
    const bf16_t* Kb = Kk + (size_t)bh * TT * HD;
    const bf16_t* Vb = Vt + (size_t)bh * HD * TT;

    // Q fragments (B-operand layout B[k=d][n=q])
    bf16x8 qf0 = *reinterpret_cast<const bf16x8*>(&Qb[(size_t)(qbase + col16)*HD + quad*8]);
    bf16x8 qf1 = *reinterpret_cast<const bf16x8*>(&Qb[(size_t)(qbase + col16)*HD + 32 + quad*8]);

    // staging geometry: each shot = 256 threads x 16B = 4KB = 32 rows x 64 cols.
    // LDS[row*64 + ch*8 + i] = src[row][(ch ^ (row&7))*8 + i]  (XOR swizzle).
    const int srow = (tid >> 3) & 31;
    const int sg   = ((lane & 7) ^ (srow & 7)) * 8;

    auto stage = [&](int kt, int buf) {
        const int s0 = kt * 64;
        GLDS16(&Kb[(size_t)(s0 + srow)*HD + sg],        &Ks[buf][wave*512]);
        GLDS16(&Kb[(size_t)(s0 + srow + 32)*HD + sg],   &Ks[buf][2048 + wave*512]);
        GLDS16(&Vb[(size_t)srow*TT + s0 + sg],          &Vs[buf][wave*512]);
        GLDS16(&Vb[(size_t)(srow + 32)*TT + s0 + sg],   &Vs[buf][2048 + wave*512]);
    };

    f32x4 acc[4];    // out^T: acc[c][r] = O^T[d = c*16+quad*4+r][q = col16]
#pragma unroll
    for (int i = 0; i < 4; i++) acc[i] = (f32x4){0.f,0.f,0.f,0.f};
    float lsum = 0.f;

    const int x7 = col16 & 7;
    const int a1 = ((quad & 1) * 32 + col16) * 4;
    const int a2 = a1 + 64;
    const bool hi = quad >= 2;

    stage(0, 0);
    __syncthreads();

    for (int kt = 0; kt < nkt; kt++) {
        const int buf = kt & 1;
        if (kt + 1 < nkt) stage(kt + 1, buf ^ 1);   // async prefetch, drained by end barrier
        const int s0 = kt * 64;
        const bool diag = (kt == nkt - 1);

        // ---- S^T = K Q^T, softmax (scale pre-baked into Q), pack P^T ----
        int pk[4][2];
#pragma unroll
        for (int c = 0; c < 4; c++) {
            bf16x8 k0 = *reinterpret_cast<const bf16x8*>(
                &Ks[buf][(c*16 + col16)*64 + ((0*4 + quad) ^ x7)*8]);
            bf16x8 k1 = *reinterpret_cast<const bf16x8*>(
                &Ks[buf][(c*16 + col16)*64 + ((1*4 + quad) ^ x7)*8]);
            f32x4 sv = __builtin_amdgcn_mfma_f32_16x16x32_bf16(k0, qf0, (f32x4){0.f,0.f,0.f,0.f}, 0, 0, 0);
            sv       = __builtin_amdgcn_mfma_f32_16x16x32_bf16(k1, qf1, sv, 0, 0, 0);

            float pr[4];
#pragma unroll
            for (int r = 0; r < 4; r++) pr[r] = exp2f(sv[r]);
            if (diag) {
#pragma unroll
                for (int r = 0; r < 4; r++)
                    if (s0 + c*16 + quad*4 + r > qbase + col16) pr[r] = 0.f;
            }
            lsum += (pr[0] + pr[1]) + (pr[2] + pr[3]);
            pk[c][0] = pack_bf16(pr[0], pr[1]);
            pk[c][1] = pack_bf16(pr[2], pr[3]);
        }

        // ---- PV: out^T += V^T P^T over 2 key-chunks of 32 ----
#pragma unroll
        for (int kc = 0; kc < 2; kc++) {
            int b0l = __builtin_amdgcn_ds_bpermute(a1, pk[2*kc][0]);
            int b0h = __builtin_amdgcn_ds_bpermute(a1, pk[2*kc+1][0]);
            int b1l = __builtin_amdgcn_ds_bpermute(a1, pk[2*kc][1]);
            int b1h = __builtin_amdgcn_ds_bpermute(a1, pk[2*kc+1][1]);
            int b2l = __builtin_amdgcn_ds_bpermute(a2, pk[2*kc][0]);
            int b2h = __builtin_amdgcn_ds_bpermute(a2, pk[2*kc+1][0]);
            int b3l = __builtin_amdgcn_ds_bpermute(a2, pk[2*kc][1]);
            int b3h = __builtin_amdgcn_ds_bpermute(a2, pk[2*kc+1][1]);
            int4 bi = { hi ? b0h : b0l, hi ? b1h : b1l, hi ? b2h : b2l, hi ? b3h : b3l };
            bf16x8 pf = __builtin_bit_cast(bf16x8, bi);
#pragma unroll
            for (int c = 0; c < 4; c++) {
                bf16x8 vf = *reinterpret_cast<const bf16x8*>(
                    &Vs[buf][(c*16 + col16)*64 + ((kc*4 + quad) ^ x7)*8]);
                acc[c] = __builtin_amdgcn_mfma_f32_16x16x32_bf16(vf, pf, acc[c], 0, 0, 0);
            }
        }
        __syncthreads();
    }

    // softmax denom: sum partials across quads (same query col16)
    float l = lsum;
    l += __shfl_xor(l, 16);
    l += __shfl_xor(l, 32);
    const float inv = 1.0f / l;

    // O write: [B,T,H,D]; lane owns query t=qbase+col16, d = c*16+quad*4+{0..3}
    const int b_ = bh >> 4, h = bh & 15;
    const int t = qbase + col16;
    bf16_t* Ob = &O[(((size_t)(b_*TT + t))*HEADS + h)*HD + quad*4];
#pragma unroll
    for (int c = 0; c < 4; c++) {
        bf16x4 o4;
#pragma unroll
        for (int r = 0; r < 4; r++) o4[r] = (bf16_t)(acc[c][r] * inv);
        *reinterpret_cast<bf16x4*>(&Ob[c*16]) = o4;
    }
}

// ---------------- launch ----------------
extern "C" void kernel_launch(void* const* d_in, const int* in_sizes, int n_in,
                              void* d_out, int out_size, void* d_ws, size_t ws_size,
                              hipStream_t stream) {
    const float* x  = (const float*)d_in[0];
    const float* Wq = (const float*)d_in[1];
    const float* Wk = (const float*)d_in[2];
    const float* Wv = (const float*)d_in[3];
    const float* Wo = (const float*)d_in[4];
    float* out = (float*)d_out;

    // workspace layout (bf16 elements), contiguous, 48 MB total
    bf16_t* Xb  = (bf16_t*)d_ws;                       // 4M
    bf16_t* Wqb = Xb  + (size_t)MROWS * D_MODEL;       // 3M (Wq|Wk|Wv)
    bf16_t* Wob = Wqb + (size_t)3 * D_MODEL * D_MODEL; // 1M
    bf16_t* Qw  = Wob + (size_t)D_MODEL * D_MODEL;     // 4M  [B,H,T,D], pre-scaled
    bf16_t* Kw  = Qw  + (size_t)MROWS * D_MODEL;       // 4M  [B,H,T,D]
    bf16_t* Vt  = Kw  + (size_t)MROWS * D_MODEL;       // 4M  [B,H,D,T] (written by GEMM)
    bf16_t* Ow  = Vt  + (size_t)MROWS * D_MODEL;       // 4M  attn out [B,T,H,D]

    // 1) convert all inputs to bf16
    cvt_all_kernel<<<(MROWS*D_MODEL + 4*D_MODEL*D_MODEL) / 4 / 256, 256, 0, stream>>>(
        x, Wq, Wk, Wv, Wo, Xb);

    // 2) fused QKV projection; V lands directly transposed in Vt
    dim3 gqkv(3 * D_MODEL / 128, MROWS / 128);
    gemm_bt<0,128><<<gqkv, 256, 0, stream>>>(Xb, Wqb, Qw, MROWS, 3 * D_MODEL, D_MODEL);

    // 3) flash attention; 1024 blocks
    attn_kernel<<<dim3(1024), 256, 0, stream>>>(Qw, Kw, Vt, Ow);

    // 4) output projection -> fp32 d_out (64-col tiles: 512 blocks = 2/CU)
    dim3 go(D_MODEL / 64, MROWS / 128);
    gemm_bt<2,64><<<go, 256, 0, stream>>>(Ow, Wob, out, MROWS, D_MODEL, D_MODEL);
}